// Round 20
// baseline (436.697 us; speedup 1.0000x reference)
//
#include <hip/hip_runtime.h>
#include <math.h>

// RWKV6 block on MI355X. fp32 problem; GEMMs in pure bf16 MFMA (absmax 0.0195
// vs 0.086 threshold). B=4, T=2048, C=2048.
// R20: 128x128 tile, BK=64, 4 waves, 64KB LDS -> 2 blocks/CU (two independent
// sync domains per CU; cross-block overlap fills barrier stalls). Same XOR
// slot swizzle, linear-dest staging, 2-phase K-loop with counted vmcnt(4),
// setprio. Per-acc K order unchanged (bit-identical to R13/R16).
// WKV recurrence via chunked parallel scan (32 chunks of 64), fp32 buffers.
constexpr int B_ = 4;
constexpr int T_ = 2048;
constexpr int C_ = 2048;
constexpr int M_ = B_ * T_;          // 8192 rows
constexpr float EPS_ = 1e-5f;
constexpr int KSTEPS = C_ / 64;      // 32
constexpr int NCH = 32;              // scan chunks
constexpr int CHL = T_ / NCH;        // 64 steps/chunk

typedef __attribute__((ext_vector_type(8))) short short8;   // bf16x8 MFMA operand
typedef __attribute__((ext_vector_type(4))) float f32x4;    // MFMA acc

__device__ __forceinline__ unsigned short rne_bf16(float x) {
    unsigned u = __float_as_uint(x);
    unsigned r = u + 0x7FFFu + ((u >> 16) & 1u);
    return (unsigned short)(r >> 16);
}

// -------- fused LayerNorm (rows m, m-1) + 3x time-mix -> bf16 planes --------
__global__ __launch_bounds__(256) void ln_mix3_kernel(
        const float* __restrict__ x,
        const float* __restrict__ w,
        const float* __restrict__ bias,
        const float* __restrict__ mxk,
        const float* __restrict__ mxv,
        const float* __restrict__ mxr,
        unsigned short* __restrict__ ak,
        unsigned short* __restrict__ av,
        unsigned short* __restrict__ ar) {
    const int m = blockIdx.x;
    const int tid = threadIdx.x;
    const bool hasPrev = (m & (T_ - 1)) != 0;
    const float* xm = x + (size_t)m * C_;

    float4 a0 = ((const float4*)xm)[tid];
    float4 a1 = ((const float4*)xm)[tid + 256];
    float4 p0 = make_float4(0.f, 0.f, 0.f, 0.f), p1 = p0;
    if (hasPrev) {
        p0 = ((const float4*)(xm - C_))[tid];
        p1 = ((const float4*)(xm - C_))[tid + 256];
    }

    float sm = a0.x + a0.y + a0.z + a0.w + a1.x + a1.y + a1.z + a1.w;
    float qm = a0.x*a0.x + a0.y*a0.y + a0.z*a0.z + a0.w*a0.w
             + a1.x*a1.x + a1.y*a1.y + a1.z*a1.z + a1.w*a1.w;
    float sp = p0.x + p0.y + p0.z + p0.w + p1.x + p1.y + p1.z + p1.w;
    float qp = p0.x*p0.x + p0.y*p0.y + p0.z*p0.z + p0.w*p0.w
             + p1.x*p1.x + p1.y*p1.y + p1.z*p1.z + p1.w*p1.w;

    #pragma unroll
    for (int off = 32; off > 0; off >>= 1) {
        sm += __shfl_down(sm, off, 64);
        qm += __shfl_down(qm, off, 64);
        sp += __shfl_down(sp, off, 64);
        qp += __shfl_down(qp, off, 64);
    }
    __shared__ float red[20];
    const int wid = tid >> 6, lane = tid & 63;
    if (lane == 0) {
        red[wid * 4 + 0] = sm; red[wid * 4 + 1] = qm;
        red[wid * 4 + 2] = sp; red[wid * 4 + 3] = qp;
    }
    __syncthreads();
    if (tid == 0) {
        float tsm = 0.f, tqm = 0.f, tsp = 0.f, tqp = 0.f;
        #pragma unroll
        for (int i = 0; i < 4; ++i) {
            tsm += red[i * 4 + 0]; tqm += red[i * 4 + 1];
            tsp += red[i * 4 + 2]; tqp += red[i * 4 + 3];
        }
        const float mum = tsm / (float)C_;
        const float varm = tqm / (float)C_ - mum * mum;
        const float mup = tsp / (float)C_;
        const float varp = tqp / (float)C_ - mup * mup;
        red[16] = mum; red[17] = rsqrtf(varm + EPS_);
        red[18] = mup; red[19] = rsqrtf(varp + EPS_);
    }
    __syncthreads();
    const float mum = red[16], rsm = red[17];
    const float mup = red[18], rsp = red[19];

    float4 w0 = ((const float4*)w)[tid];
    float4 w1 = ((const float4*)w)[tid + 256];
    float4 b0 = ((const float4*)bias)[tid];
    float4 b1 = ((const float4*)bias)[tid + 256];

    const float avv[8] = {a0.x, a0.y, a0.z, a0.w, a1.x, a1.y, a1.z, a1.w};
    const float pvv[8] = {p0.x, p0.y, p0.z, p0.w, p1.x, p1.y, p1.z, p1.w};
    const float wvv[8] = {w0.x, w0.y, w0.z, w0.w, w1.x, w1.y, w1.z, w1.w};
    const float bvv[8] = {b0.x, b0.y, b0.z, b0.w, b1.x, b1.y, b1.z, b1.w};

    float lm[8], lp[8];
    #pragma unroll
    for (int j = 0; j < 8; ++j) {
        lm[j] = (avv[j] - mum) * rsm * wvv[j] + bvv[j];
        lp[j] = hasPrev ? (pvv[j] - mup) * rsp * wvv[j] + bvv[j] : 0.f;  // prev=0 at t=0
    }

    const size_t rowbase = (size_t)m * C_;
    auto emit = [&](const float* __restrict__ mx, unsigned short* __restrict__ hi) {
        float4 m0 = ((const float4*)mx)[tid];
        float4 m1 = ((const float4*)mx)[tid + 256];
        const float mm[8] = {m0.x, m0.y, m0.z, m0.w, m1.x, m1.y, m1.z, m1.w};
        ushort4 h[2];
        #pragma unroll
        for (int half = 0; half < 2; ++half) {
            unsigned short hh[4];
            #pragma unroll
            for (int j = 0; j < 4; ++j) {
                const int c = half * 4 + j;
                hh[j] = rne_bf16(lp[c] + (lm[c] - lp[c]) * mm[c]);
            }
            h[half].x = hh[0]; h[half].y = hh[1]; h[half].z = hh[2]; h[half].w = hh[3];
        }
        ((ushort4*)(hi + rowbase))[tid] = h[0];
        ((ushort4*)(hi + rowbase))[tid + 256] = h[1];
    };
    emit(mxk, ak);
    emit(mxv, av);
    emit(mxr, ar);
}

// ---------------- W fp32 -> bf16 plane ----------------
__global__ __launch_bounds__(256) void wconv_kernel(const float* __restrict__ W,
                                                    unsigned short* __restrict__ hi) {
    const int i = blockIdx.x * 256 + threadIdx.x;   // over C_*C_/4 float4s
    float4 w = ((const float4*)W)[i];
    ushort4 h;
    h.x = rne_bf16(w.x);
    h.y = rne_bf16(w.y);
    h.z = rne_bf16(w.z);
    h.w = rne_bf16(w.w);
    ((ushort4*)hi)[i] = h;
}

// ---------------- MFMA GEMM: Y[m,n] = sum_k A[m,k] * W[n,k], bf16 --------
// 128x128 tile, BK=64, 256 threads (4 waves 2Mx2N, 64x64/wave as 4x4 frags).
// 64KB LDS double-buffer -> 2 blocks/CU (independent sync domains).
// Per region 128 rows x 8 slots of 16B (slot s = k-chunk s*8..s*8+7), physical
// slot p = s ^ (row&7); global_load_lds dest linear, per-lane GLOBAL source
// pre-applies the inverse swizzle (8 issues/thread/tile, 4 A + 4 B).
// 2 phases per K-step (one mi-pair x 4 ni x 2 k-subtiles = 16 MFMA each);
// counted vmcnt(4) at phase 0 (tile t's 8 drained, 4 of t+1 in flight).
template <bool SIG>
__global__ __launch_bounds__(256, 2) void gemm_mfma(const unsigned short* __restrict__ Ahi,
                                                    const unsigned short* __restrict__ Whi,
                                                    float* __restrict__ Y) {
    __shared__ unsigned short lds[2][2][128 * 64];   // 64 KB total

    const int tid = threadIdx.x;
    const int lane = tid & 63;
    const int wid = tid >> 6;          // 0..3
    const int wr = wid >> 1;           // 0..1  (M half: 64 rows)
    const int wc = wid & 1;            // 0..1  (N half: 64 cols)

    // XCD-chunked block swizzle: 1024 blocks, 8 XCDs, 128/XCD (1024%8==0)
    const int bid = blockIdx.x;
    const int swz = (bid & 7) * 128 + (bid >> 3);
    const int m0 = (swz >> 4) * 128;   // 64 M-blocks
    const int n0 = (swz & 15) * 128;   // 16 N-blocks

    const unsigned short* gA[4];
    const unsigned short* gB[4];
    #pragma unroll
    for (int j = 0; j < 4; ++j) {
        const int ci = j * 256 + tid;   // 0..1023 over 128x8 chunks
        const int r = ci >> 3, p = ci & 7;
        const int s = p ^ (r & 7);      // logical k-chunk 0..7 within BK=64
        gA[j] = Ahi + (size_t)(m0 + r) * C_ + s * 8;
        gB[j] = Whi + (size_t)(n0 + r) * C_ + s * 8;
    }
    const int stage_off = wid * 512;    // ushorts; dest = j*2048 + stage_off

    const int fr = lane & 15;
    const int kg = lane >> 4;
    const int pS0 = (kg + 0) ^ (fr & 7);   // k-subtile 0 (k 0..31)
    const int pS1 = (kg + 4) ^ (fr & 7);   // k-subtile 1 (k 32..63)
    const int baseA0 = (wr * 64 + fr) * 64 + pS0 * 8;
    const int baseA1 = (wr * 64 + fr) * 64 + pS1 * 8;
    const int baseB0 = (wc * 64 + fr) * 64 + pS0 * 8;
    const int baseB1 = (wc * 64 + fr) * 64 + pS1 * 8;

    f32x4 acc[4][4] = {};

    auto ISSUE = [&](int buf, int t, int j) {
        const int ko = t * 64;
        __builtin_amdgcn_global_load_lds(
            (const __attribute__((address_space(1))) unsigned int*)(gA[j] + ko),
            (__attribute__((address_space(3))) unsigned int*)&lds[buf][0][j * 2048 + stage_off],
            16, 0, 0);
        __builtin_amdgcn_global_load_lds(
            (const __attribute__((address_space(1))) unsigned int*)(gB[j] + ko),
            (__attribute__((address_space(3))) unsigned int*)&lds[buf][1][j * 2048 + stage_off],
            16, 0, 0);
    };

    // one mi-pair over both k-subtiles: 16 MFMAs; per-acc K order ascending.
    auto MFMA_PAIR = [&](int mi0, const short8& a0s0, const short8& a0s1,
                         const short8& a1s0, const short8& a1s1,
                         const short8* b0, const short8* b1) {
        #pragma unroll
        for (int ni = 0; ni < 4; ++ni) {   // k-subtile 0
            acc[mi0][ni]     = __builtin_amdgcn_mfma_f32_16x16x32_bf16(a0s0, b0[ni], acc[mi0][ni], 0, 0, 0);
            acc[mi0 + 1][ni] = __builtin_amdgcn_mfma_f32_16x16x32_bf16(a1s0, b0[ni], acc[mi0 + 1][ni], 0, 0, 0);
        }
        #pragma unroll
        for (int ni = 0; ni < 4; ++ni) {   // k-subtile 1
            acc[mi0][ni]     = __builtin_amdgcn_mfma_f32_16x16x32_bf16(a0s1, b1[ni], acc[mi0][ni], 0, 0, 0);
            acc[mi0 + 1][ni] = __builtin_amdgcn_mfma_f32_16x16x32_bf16(a1s1, b1[ni], acc[mi0 + 1][ni], 0, 0, 0);
        }
    };

    // prologue: stage tile 0 (8 loads/thread)
    #pragma unroll
    for (int j = 0; j < 4; ++j) ISSUE(0, 0, j);

    for (int t = 0; t < KSTEPS; ++t) {
        const int cur = t & 1, nxt = cur ^ 1;
        const bool last = (t == KSTEPS - 1);
        const unsigned short* LA = lds[cur][0];
        const unsigned short* LB = lds[cur][1];

        short8 b0[4], b1[4];

        // ---------- phase 0 (mi 0,1): validate buf cur, read B frags ----------
        if (!last) {
            ISSUE(nxt, t + 1, 0);
            ISSUE(nxt, t + 1, 1);
            asm volatile("s_waitcnt vmcnt(4)" ::: "memory");  // tile t's 8 done
        } else {
            asm volatile("s_waitcnt vmcnt(0)" ::: "memory");
        }
        __builtin_amdgcn_s_barrier();
        #pragma unroll
        for (int ni = 0; ni < 4; ++ni) {
            b0[ni] = *(const short8*)&LB[baseB0 + ni * 1024];
            b1[ni] = *(const short8*)&LB[baseB1 + ni * 1024];
        }
        {
            const short8 a0s0 = *(const short8*)&LA[baseA0 + 0 * 1024];
            const short8 a0s1 = *(const short8*)&LA[baseA1 + 0 * 1024];
            const short8 a1s0 = *(const short8*)&LA[baseA0 + 1 * 1024];
            const short8 a1s1 = *(const short8*)&LA[baseA1 + 1 * 1024];
            asm volatile("s_waitcnt lgkmcnt(0)" ::: "memory");
            __builtin_amdgcn_s_setprio(1);
            MFMA_PAIR(0, a0s0, a0s1, a1s0, a1s1, b0, b1);
            __builtin_amdgcn_s_setprio(0);
        }
        __builtin_amdgcn_s_barrier();

        // ---------- phase 1 (mi 2,3) ----------
        {
            const short8 a0s0 = *(const short8*)&LA[baseA0 + 2 * 1024];
            const short8 a0s1 = *(const short8*)&LA[baseA1 + 2 * 1024];
            const short8 a1s0 = *(const short8*)&LA[baseA0 + 3 * 1024];
            const short8 a1s1 = *(const short8*)&LA[baseA1 + 3 * 1024];
            if (!last) {
                ISSUE(nxt, t + 1, 2);
                ISSUE(nxt, t + 1, 3);
            }
            __builtin_amdgcn_s_barrier();
            asm volatile("s_waitcnt lgkmcnt(0)" ::: "memory");
            __builtin_amdgcn_s_setprio(1);
            MFMA_PAIR(2, a0s0, a0s1, a1s0, a1s1, b0, b1);
            __builtin_amdgcn_s_setprio(0);
            __builtin_amdgcn_s_barrier();
        }
    }

    // ---- epilogue: C/D layout col=lane&15, row=(lane>>4)*4+reg ----
    const int orow = m0 + wr * 64 + (lane >> 4) * 4;
    const int ocol = n0 + wc * 64 + fr;
    #pragma unroll
    for (int mi = 0; mi < 4; ++mi)
        #pragma unroll
        for (int ni = 0; ni < 4; ++ni)
            #pragma unroll
            for (int rr = 0; rr < 4; ++rr) {
                float v = acc[mi][ni][rr];
                if (SIG) v = 1.f / (1.f + expf(-v));
                Y[(size_t)(orow + mi * 16 + rr) * C_ + ocol + ni * 16] = v;
            }
}

// ---------------- WKV chunked scan, pass 1: per-chunk local end state ----
__global__ __launch_bounds__(256) void wkv_scan1(const float* __restrict__ k,
                                                 const float* __restrict__ time_decay,
                                                 float* __restrict__ chend) {
    const int c0 = (blockIdx.x * 256 + threadIdx.x) * 2;
    const int j = blockIdx.y;
    const int b = blockIdx.z;
    const float2 td = *(const float2*)&time_decay[c0];
    const float d0 = 1.f / (1.f + expf(-td.x));
    const float d1 = 1.f / (1.f + expf(-td.y));
    size_t base = ((size_t)b * T_ + (size_t)j * CHL) * C_ + c0;
    float s0 = 0.f, s1 = 0.f;
    #pragma unroll 8
    for (int t = 0; t < CHL; ++t) {
        const float2 kt = *(const float2*)&k[base];
        s0 = s0 * d0 + kt.x;
        s1 = s1 * d1 + kt.y;
        base += C_;
    }
    *(float2*)&chend[((size_t)b * NCH + j) * C_ + c0] = make_float2(s0, s1);
}

// ---------------- WKV chunked scan, pass 2: carry-in + rescan + fuse -----
__global__ __launch_bounds__(256) void wkv_scan2(const float* __restrict__ k,
                                                 const float* __restrict__ v,
                                                 const float* __restrict__ r,
                                                 const float* __restrict__ time_decay,
                                                 const float* __restrict__ time_first,
                                                 const float* __restrict__ chend,
                                                 unsigned short* __restrict__ yhi) {
    const int c0 = (blockIdx.x * 256 + threadIdx.x) * 2;
    const int j = blockIdx.y;
    const int b = blockIdx.z;
    const float2 td = *(const float2*)&time_decay[c0];
    const float2 tf = *(const float2*)&time_first[c0];
    const float d0 = 1.f / (1.f + expf(-td.x));
    const float d1 = 1.f / (1.f + expf(-td.y));
    const float f0 = expf(tf.x);
    const float f1 = expf(tf.y);

    float dL0 = d0, dL1 = d1;           // d^CHL, CHL=64 -> 6 squarings
    #pragma unroll
    for (int i = 0; i < 6; ++i) { dL0 *= dL0; dL1 *= dL1; }

    float s0 = 0.f, s1 = 0.f;
    for (int i = 0; i < j; ++i) {
        const float2 e = *(const float2*)&chend[((size_t)b * NCH + i) * C_ + c0];
        s0 = s0 * dL0 + e.x;
        s1 = s1 * dL1 + e.y;
    }

    size_t base = ((size_t)b * T_ + (size_t)j * CHL) * C_ + c0;
    #pragma unroll 4
    for (int t = 0; t < CHL; ++t) {
        const float2 kt = *(const float2*)&k[base];
        const float2 vt = *(const float2*)&v[base];
        const float2 rt = *(const float2*)&r[base];
        s0 = s0 * d0 + kt.x;
        s1 = s1 * d1 + kt.y;
        const float y0 = rt.x * ((s0 * f0 + kt.x) * vt.x);
        const float y1 = rt.y * ((s1 * f1 + kt.y) * vt.y);
        ushort2 ph; ph.x = rne_bf16(y0); ph.y = rne_bf16(y1);
        *(ushort2*)&yhi[base] = ph;
        base += C_;
    }
}

// ---------------- launch ----------------
extern "C" void kernel_launch(void* const* d_in, const int* in_sizes, int n_in,
                              void* d_out, int out_size, void* d_ws, size_t ws_size,
                              hipStream_t stream) {
    const float* x          = (const float*)d_in[0];
    const float* ln_w       = (const float*)d_in[1];
    const float* ln_b       = (const float*)d_in[2];
    const float* mix_k      = (const float*)d_in[3];
    const float* mix_v      = (const float*)d_in[4];
    const float* mix_r      = (const float*)d_in[5];
    const float* time_decay = (const float*)d_in[6];
    const float* time_first = (const float*)d_in[7];
    const float* Wk         = (const float*)d_in[8];
    const float* Wv         = (const float*)d_in[9];
    const float* Wr         = (const float*)d_in[10];
    const float* Wo         = (const float*)d_in[11];
    float* out = (float*)d_out;

    // ws (~201 MiB, region layout kept for aliasing):
    //   R0 = [akhi | spare] | R1 = [avhi | spare] | R2 = [arhi | spare] | R3 = W
    // Aliases: kb (fp32 64MB) -> R2 (Ar dead after r-GEMM); vb -> R0 (Ak dead
    // after k-GEMM); yhi -> R1 head (Av dead after v-GEMM); chend -> R3 (W dead
    // between v-GEMM and Wo wconv); rb -> d_out.
    const size_t planeElems = (size_t)M_ * C_;
    unsigned short* akhi = (unsigned short*)d_ws;
    unsigned short* avhi = akhi + 2 * planeElems;
    unsigned short* arhi = avhi + 2 * planeElems;
    unsigned short* whi  = arhi + 2 * planeElems;

    float* kb = (float*)arhi;
    float* vb = (float*)akhi;
    float* rb = out;
    unsigned short* yhi = avhi;
    float* chend = (float*)whi;

    const int wcBlocks = (C_ * C_ / 4) / 256;           // 4096
    const int gemmBlocks = (M_ / 128) * (C_ / 128);     // 1024
    const dim3 wkvGrid(C_ / 512, NCH, B_);

    // 1. fused LN + 3x mix -> bf16 A planes
    ln_mix3_kernel<<<M_, 256, 0, stream>>>(x, ln_w, ln_b, mix_k, mix_v, mix_r,
                                           akhi, avhi, arhi);

    // 2. r projection (sigmoid fused) -> fp32 d_out
    wconv_kernel<<<wcBlocks, 256, 0, stream>>>(Wr, whi);
    gemm_mfma<true><<<gemmBlocks, 256, 0, stream>>>(arhi, whi, rb);

    // 3. k projection -> kb (over Ar region)
    wconv_kernel<<<wcBlocks, 256, 0, stream>>>(Wk, whi);
    gemm_mfma<false><<<gemmBlocks, 256, 0, stream>>>(akhi, whi, kb);

    // 4. v projection -> vb (over Ak region)
    wconv_kernel<<<wcBlocks, 256, 0, stream>>>(Wv, whi);
    gemm_mfma<false><<<gemmBlocks, 256, 0, stream>>>(avhi, whi, vb);

    // 5. WKV chunked scan -> y bf16 plane (over Av region; chend over W region)
    wkv_scan1<<<wkvGrid, 256, 0, stream>>>(kb, time_decay, chend);
    wkv_scan2<<<wkvGrid, 256, 0, stream>>>(kb, vb, rb, time_decay, time_first, chend,
                                           yhi);

    // 6. output projection (wconv overwrites chend only after scan2 done)
    wconv_kernel<<<wcBlocks, 256, 0, stream>>>(Wo, whi);
    gemm_mfma<false><<<gemmBlocks, 256, 0, stream>>>(yhi, whi, out);
}

// Round 21
// 361.103 us; speedup vs baseline: 1.2093x; 1.2093x over previous
//
#include <hip/hip_runtime.h>
#include <math.h>

// RWKV6 block on MI355X. fp32 problem; GEMMs in pure bf16 MFMA. B=4,T=2048,C=2048.
// R21 = R13 (best measured: 382.6 us) + bf16 k/v/r intermediates:
// projection GEMMs store bf16 (halves GEMM write + WKV scan read traffic);
// WKV scans read bf16, compute fp32. GEMM K-loop bit-identical to R13.
constexpr int B_ = 4;
constexpr int T_ = 2048;
constexpr int C_ = 2048;
constexpr int M_ = B_ * T_;          // 8192 rows
constexpr float EPS_ = 1e-5f;
constexpr int KSTEPS = C_ / 64;      // 32
constexpr int NCH = 32;              // scan chunks
constexpr int CHL = T_ / NCH;        // 64 steps/chunk

typedef __attribute__((ext_vector_type(8))) short short8;   // bf16x8 MFMA operand
typedef __attribute__((ext_vector_type(4))) float f32x4;    // MFMA acc

__device__ __forceinline__ unsigned short rne_bf16(float x) {
    unsigned u = __float_as_uint(x);
    unsigned r = u + 0x7FFFu + ((u >> 16) & 1u);
    return (unsigned short)(r >> 16);
}
__device__ __forceinline__ float bf16_to_f32(unsigned short h) {
    return __uint_as_float((unsigned)h << 16);
}

// -------- fused LayerNorm (rows m, m-1) + 3x time-mix -> bf16 planes --------
__global__ __launch_bounds__(256) void ln_mix3_kernel(
        const float* __restrict__ x,
        const float* __restrict__ w,
        const float* __restrict__ bias,
        const float* __restrict__ mxk,
        const float* __restrict__ mxv,
        const float* __restrict__ mxr,
        unsigned short* __restrict__ ak,
        unsigned short* __restrict__ av,
        unsigned short* __restrict__ ar) {
    const int m = blockIdx.x;
    const int tid = threadIdx.x;
    const bool hasPrev = (m & (T_ - 1)) != 0;
    const float* xm = x + (size_t)m * C_;

    float4 a0 = ((const float4*)xm)[tid];
    float4 a1 = ((const float4*)xm)[tid + 256];
    float4 p0 = make_float4(0.f, 0.f, 0.f, 0.f), p1 = p0;
    if (hasPrev) {
        p0 = ((const float4*)(xm - C_))[tid];
        p1 = ((const float4*)(xm - C_))[tid + 256];
    }

    float sm = a0.x + a0.y + a0.z + a0.w + a1.x + a1.y + a1.z + a1.w;
    float qm = a0.x*a0.x + a0.y*a0.y + a0.z*a0.z + a0.w*a0.w
             + a1.x*a1.x + a1.y*a1.y + a1.z*a1.z + a1.w*a1.w;
    float sp = p0.x + p0.y + p0.z + p0.w + p1.x + p1.y + p1.z + p1.w;
    float qp = p0.x*p0.x + p0.y*p0.y + p0.z*p0.z + p0.w*p0.w
             + p1.x*p1.x + p1.y*p1.y + p1.z*p1.z + p1.w*p1.w;

    #pragma unroll
    for (int off = 32; off > 0; off >>= 1) {
        sm += __shfl_down(sm, off, 64);
        qm += __shfl_down(qm, off, 64);
        sp += __shfl_down(sp, off, 64);
        qp += __shfl_down(qp, off, 64);
    }
    __shared__ float red[20];
    const int wid = tid >> 6, lane = tid & 63;
    if (lane == 0) {
        red[wid * 4 + 0] = sm; red[wid * 4 + 1] = qm;
        red[wid * 4 + 2] = sp; red[wid * 4 + 3] = qp;
    }
    __syncthreads();
    if (tid == 0) {
        float tsm = 0.f, tqm = 0.f, tsp = 0.f, tqp = 0.f;
        #pragma unroll
        for (int i = 0; i < 4; ++i) {
            tsm += red[i * 4 + 0]; tqm += red[i * 4 + 1];
            tsp += red[i * 4 + 2]; tqp += red[i * 4 + 3];
        }
        const float mum = tsm / (float)C_;
        const float varm = tqm / (float)C_ - mum * mum;
        const float mup = tsp / (float)C_;
        const float varp = tqp / (float)C_ - mup * mup;
        red[16] = mum; red[17] = rsqrtf(varm + EPS_);
        red[18] = mup; red[19] = rsqrtf(varp + EPS_);
    }
    __syncthreads();
    const float mum = red[16], rsm = red[17];
    const float mup = red[18], rsp = red[19];

    float4 w0 = ((const float4*)w)[tid];
    float4 w1 = ((const float4*)w)[tid + 256];
    float4 b0 = ((const float4*)bias)[tid];
    float4 b1 = ((const float4*)bias)[tid + 256];

    const float avv[8] = {a0.x, a0.y, a0.z, a0.w, a1.x, a1.y, a1.z, a1.w};
    const float pvv[8] = {p0.x, p0.y, p0.z, p0.w, p1.x, p1.y, p1.z, p1.w};
    const float wvv[8] = {w0.x, w0.y, w0.z, w0.w, w1.x, w1.y, w1.z, w1.w};
    const float bvv[8] = {b0.x, b0.y, b0.z, b0.w, b1.x, b1.y, b1.z, b1.w};

    float lm[8], lp[8];
    #pragma unroll
    for (int j = 0; j < 8; ++j) {
        lm[j] = (avv[j] - mum) * rsm * wvv[j] + bvv[j];
        lp[j] = hasPrev ? (pvv[j] - mup) * rsp * wvv[j] + bvv[j] : 0.f;  // prev=0 at t=0
    }

    const size_t rowbase = (size_t)m * C_;
    auto emit = [&](const float* __restrict__ mx, unsigned short* __restrict__ hi) {
        float4 m0 = ((const float4*)mx)[tid];
        float4 m1 = ((const float4*)mx)[tid + 256];
        const float mm[8] = {m0.x, m0.y, m0.z, m0.w, m1.x, m1.y, m1.z, m1.w};
        ushort4 h[2];
        #pragma unroll
        for (int half = 0; half < 2; ++half) {
            unsigned short hh[4];
            #pragma unroll
            for (int j = 0; j < 4; ++j) {
                const int c = half * 4 + j;
                hh[j] = rne_bf16(lp[c] + (lm[c] - lp[c]) * mm[c]);
            }
            h[half].x = hh[0]; h[half].y = hh[1]; h[half].z = hh[2]; h[half].w = hh[3];
        }
        ((ushort4*)(hi + rowbase))[tid] = h[0];
        ((ushort4*)(hi + rowbase))[tid + 256] = h[1];
    };
    emit(mxk, ak);
    emit(mxv, av);
    emit(mxr, ar);
}

// ---------------- W fp32 -> bf16 plane ----------------
__global__ __launch_bounds__(256) void wconv_kernel(const float* __restrict__ W,
                                                    unsigned short* __restrict__ hi) {
    const int i = blockIdx.x * 256 + threadIdx.x;   // over C_*C_/4 float4s
    float4 w = ((const float4*)W)[i];
    ushort4 h;
    h.x = rne_bf16(w.x);
    h.y = rne_bf16(w.y);
    h.z = rne_bf16(w.z);
    h.w = rne_bf16(w.w);
    ((ushort4*)hi)[i] = h;
}

// ---------------- MFMA GEMM: Y[m,n] = sum_k A[m,k] * W[n,k], bf16 --------
// 256x256 tile, BK=64, 512 threads (8 waves, 2Mx4N). 128KB LDS double-buffer;
// per region 256 rows x 8 slots of 16B (slot s = k-chunk s*8..s*8+7), physical
// slot p = s ^ (row&7); global_load_lds dest linear, per-lane GLOBAL source
// pre-applies the inverse swizzle (8 issues/thread/tile).
// 2 phases per K-step (one mi-quad x 2 k-subtiles = 32 MFMA each), counted
// vmcnt(4), setprio. (R13 structure verbatim; measured 80 us/GEMM.)
// OUTBF16: store bf16 (k/v/r intermediates); else fp32 (final output).
template <bool SIG, bool OUTBF16>
__global__ __launch_bounds__(512, 2) void gemm_mfma(const unsigned short* __restrict__ Ahi,
                                                    const unsigned short* __restrict__ Whi,
                                                    float* __restrict__ Yf,
                                                    unsigned short* __restrict__ Yh) {
    __shared__ unsigned short lds[2][2][256 * 64];

    const int tid = threadIdx.x;
    const int lane = tid & 63;
    const int wid = tid >> 6;          // 0..7
    const int wr = wid >> 2;           // 0..1  (M half: 128 rows)
    const int wcn = wid & 3;           // 0..3  (N quarter: 64 cols)

    // XCD-chunked block swizzle: 256 blocks, 8 XCDs, 32/XCD
    const int bid = blockIdx.x;
    const int swz = (bid & 7) * 32 + (bid >> 3);
    const int m0 = (swz >> 3) * 256;
    const int n0 = (swz & 7) * 256;

    const unsigned short* gA[4];
    const unsigned short* gB[4];
    #pragma unroll
    for (int j = 0; j < 4; ++j) {
        const int ci = j * 512 + tid;
        const int r = ci >> 3, p = ci & 7;
        const int s = p ^ (r & 7);      // logical k-chunk 0..7 within BK=64
        gA[j] = Ahi + (size_t)(m0 + r) * C_ + s * 8;
        gB[j] = Whi + (size_t)(n0 + r) * C_ + s * 8;
    }
    const int stage_off = wid * 512;

    const int fr = lane & 15;
    const int kg = lane >> 4;
    const int pS0 = (kg + 0) ^ (fr & 7);   // k-subtile 0 (k 0..31)
    const int pS1 = (kg + 4) ^ (fr & 7);   // k-subtile 1 (k 32..63)
    const int baseA0 = (wr * 128 + fr) * 64 + pS0 * 8;
    const int baseA1 = (wr * 128 + fr) * 64 + pS1 * 8;
    const int baseB0 = (wcn * 64 + fr) * 64 + pS0 * 8;
    const int baseB1 = (wcn * 64 + fr) * 64 + pS1 * 8;

    f32x4 acc[8][4] = {};

    auto ISSUE = [&](int buf, int t, int j) {
        const int ko = t * 64;
        __builtin_amdgcn_global_load_lds(
            (const __attribute__((address_space(1))) unsigned int*)(gA[j] + ko),
            (__attribute__((address_space(3))) unsigned int*)&lds[buf][0][j * 4096 + stage_off],
            16, 0, 0);
        __builtin_amdgcn_global_load_lds(
            (const __attribute__((address_space(1))) unsigned int*)(gB[j] + ko),
            (__attribute__((address_space(3))) unsigned int*)&lds[buf][1][j * 4096 + stage_off],
            16, 0, 0);
    };

    // one mi-quad over both k-subtiles: 32 MFMAs, sub-k-major; per-acc K
    // order ascending (bit-identical to R13/R12).
    auto MFMA_QUAD = [&](int mi0, const short8* a0, const short8* a1,
                         const short8* b0, const short8* b1) {
        #pragma unroll
        for (int ni = 0; ni < 4; ++ni)
            #pragma unroll
            for (int q = 0; q < 4; ++q)
                acc[mi0 + q][ni] = __builtin_amdgcn_mfma_f32_16x16x32_bf16(a0[q], b0[ni], acc[mi0 + q][ni], 0, 0, 0);
        #pragma unroll
        for (int ni = 0; ni < 4; ++ni)
            #pragma unroll
            for (int q = 0; q < 4; ++q)
                acc[mi0 + q][ni] = __builtin_amdgcn_mfma_f32_16x16x32_bf16(a1[q], b1[ni], acc[mi0 + q][ni], 0, 0, 0);
    };

    // prologue: stage tile 0 (8 loads/thread)
    #pragma unroll
    for (int j = 0; j < 4; ++j) ISSUE(0, 0, j);

    for (int t = 0; t < KSTEPS; ++t) {
        const int cur = t & 1, nxt = cur ^ 1;
        const bool last = (t == KSTEPS - 1);
        const unsigned short* LA = lds[cur][0];
        const unsigned short* LB = lds[cur][1];

        short8 b0[4], b1[4];

        // ---------- phase 0 (mi 0-3): validate buf cur, read B frags ----------
        if (!last) {
            ISSUE(nxt, t + 1, 0);
            ISSUE(nxt, t + 1, 1);
            asm volatile("s_waitcnt vmcnt(4)" ::: "memory");  // tile t's 8 done
        } else {
            asm volatile("s_waitcnt vmcnt(0)" ::: "memory");
        }
        __builtin_amdgcn_s_barrier();
        #pragma unroll
        for (int ni = 0; ni < 4; ++ni) {
            b0[ni] = *(const short8*)&LB[baseB0 + ni * 1024];
            b1[ni] = *(const short8*)&LB[baseB1 + ni * 1024];
        }
        {
            short8 a0[4], a1[4];
            #pragma unroll
            for (int q = 0; q < 4; ++q) {
                a0[q] = *(const short8*)&LA[baseA0 + q * 1024];
                a1[q] = *(const short8*)&LA[baseA1 + q * 1024];
            }
            asm volatile("s_waitcnt lgkmcnt(0)" ::: "memory");
            __builtin_amdgcn_s_setprio(1);
            MFMA_QUAD(0, a0, a1, b0, b1);
            __builtin_amdgcn_s_setprio(0);
        }
        __builtin_amdgcn_s_barrier();

        // ---------- phase 1 (mi 4-7) ----------
        {
            short8 a0[4], a1[4];
            #pragma unroll
            for (int q = 0; q < 4; ++q) {
                a0[q] = *(const short8*)&LA[baseA0 + (4 + q) * 1024];
                a1[q] = *(const short8*)&LA[baseA1 + (4 + q) * 1024];
            }
            if (!last) {
                ISSUE(nxt, t + 1, 2);
                ISSUE(nxt, t + 1, 3);
            }
            __builtin_amdgcn_s_barrier();
            asm volatile("s_waitcnt lgkmcnt(0)" ::: "memory");
            __builtin_amdgcn_s_setprio(1);
            MFMA_QUAD(4, a0, a1, b0, b1);
            __builtin_amdgcn_s_setprio(0);
            __builtin_amdgcn_s_barrier();
        }
    }

    // ---- epilogue: C/D layout col=lane&15, row=(lane>>4)*4+reg ----
    const int orow = m0 + wr * 128 + (lane >> 4) * 4;
    const int ocol = n0 + wcn * 64 + fr;
    #pragma unroll
    for (int mi = 0; mi < 8; ++mi)
        #pragma unroll
        for (int ni = 0; ni < 4; ++ni)
            #pragma unroll
            for (int rr = 0; rr < 4; ++rr) {
                float v = acc[mi][ni][rr];
                if (SIG) v = 1.f / (1.f + expf(-v));
                const size_t idx = (size_t)(orow + mi * 16 + rr) * C_ + ocol + ni * 16;
                if (OUTBF16) Yh[idx] = rne_bf16(v);
                else         Yf[idx] = v;
            }
}

// ---------------- WKV chunked scan, pass 1: per-chunk local end state ----
// bf16 k input; fp32 accumulation.
__global__ __launch_bounds__(256) void wkv_scan1(const unsigned short* __restrict__ k,
                                                 const float* __restrict__ time_decay,
                                                 float* __restrict__ chend) {
    const int c0 = (blockIdx.x * 256 + threadIdx.x) * 2;
    const int j = blockIdx.y;
    const int b = blockIdx.z;
    const float2 td = *(const float2*)&time_decay[c0];
    const float d0 = 1.f / (1.f + expf(-td.x));
    const float d1 = 1.f / (1.f + expf(-td.y));
    size_t base = ((size_t)b * T_ + (size_t)j * CHL) * C_ + c0;
    float s0 = 0.f, s1 = 0.f;
    #pragma unroll 8
    for (int t = 0; t < CHL; ++t) {
        const ushort2 kt = *(const ushort2*)&k[base];
        s0 = s0 * d0 + bf16_to_f32(kt.x);
        s1 = s1 * d1 + bf16_to_f32(kt.y);
        base += C_;
    }
    *(float2*)&chend[((size_t)b * NCH + j) * C_ + c0] = make_float2(s0, s1);
}

// ---------------- WKV chunked scan, pass 2: carry-in + rescan + fuse -----
// bf16 k/v/r inputs; fp32 math; bf16 y output.
__global__ __launch_bounds__(256) void wkv_scan2(const unsigned short* __restrict__ k,
                                                 const unsigned short* __restrict__ v,
                                                 const unsigned short* __restrict__ r,
                                                 const float* __restrict__ time_decay,
                                                 const float* __restrict__ time_first,
                                                 const float* __restrict__ chend,
                                                 unsigned short* __restrict__ yhi) {
    const int c0 = (blockIdx.x * 256 + threadIdx.x) * 2;
    const int j = blockIdx.y;
    const int b = blockIdx.z;
    const float2 td = *(const float2*)&time_decay[c0];
    const float2 tf = *(const float2*)&time_first[c0];
    const float d0 = 1.f / (1.f + expf(-td.x));
    const float d1 = 1.f / (1.f + expf(-td.y));
    const float f0 = expf(tf.x);
    const float f1 = expf(tf.y);

    float dL0 = d0, dL1 = d1;           // d^CHL, CHL=64 -> 6 squarings
    #pragma unroll
    for (int i = 0; i < 6; ++i) { dL0 *= dL0; dL1 *= dL1; }

    float s0 = 0.f, s1 = 0.f;
    for (int i = 0; i < j; ++i) {
        const float2 e = *(const float2*)&chend[((size_t)b * NCH + i) * C_ + c0];
        s0 = s0 * dL0 + e.x;
        s1 = s1 * dL1 + e.y;
    }

    size_t base = ((size_t)b * T_ + (size_t)j * CHL) * C_ + c0;
    #pragma unroll 4
    for (int t = 0; t < CHL; ++t) {
        const ushort2 kt = *(const ushort2*)&k[base];
        const ushort2 vt = *(const ushort2*)&v[base];
        const ushort2 rt = *(const ushort2*)&r[base];
        const float k0 = bf16_to_f32(kt.x), k1 = bf16_to_f32(kt.y);
        s0 = s0 * d0 + k0;
        s1 = s1 * d1 + k1;
        const float y0 = bf16_to_f32(rt.x) * ((s0 * f0 + k0) * bf16_to_f32(vt.x));
        const float y1 = bf16_to_f32(rt.y) * ((s1 * f1 + k1) * bf16_to_f32(vt.y));
        ushort2 ph; ph.x = rne_bf16(y0); ph.y = rne_bf16(y1);
        *(ushort2*)&yhi[base] = ph;
        base += C_;
    }
}

// ---------------- launch ----------------
extern "C" void kernel_launch(void* const* d_in, const int* in_sizes, int n_in,
                              void* d_out, int out_size, void* d_ws, size_t ws_size,
                              hipStream_t stream) {
    const float* x          = (const float*)d_in[0];
    const float* ln_w       = (const float*)d_in[1];
    const float* ln_b       = (const float*)d_in[2];
    const float* mix_k      = (const float*)d_in[3];
    const float* mix_v      = (const float*)d_in[4];
    const float* mix_r      = (const float*)d_in[5];
    const float* time_decay = (const float*)d_in[6];
    const float* time_first = (const float*)d_in[7];
    const float* Wk         = (const float*)d_in[8];
    const float* Wv         = (const float*)d_in[9];
    const float* Wr         = (const float*)d_in[10];
    const float* Wo         = (const float*)d_in[11];
    float* out = (float*)d_out;

    // ws (~201 MiB, region layout kept for aliasing):
    //   R0 = [akhi | spare] | R1 = [avhi | spare] | R2 = [arhi | spare] | R3 = W
    // Aliases (all bf16 now): kb -> R2 head (Ar dead after r-GEMM); vb -> R0
    // head (Ak dead after k-GEMM); yhi -> R1 head (Av dead after v-GEMM);
    // chend -> R3 (W dead between v-GEMM and Wo wconv); rb -> d_out as bf16
    // (consumed by scan2 before out-GEMM overwrites d_out with fp32).
    const size_t planeElems = (size_t)M_ * C_;
    unsigned short* akhi = (unsigned short*)d_ws;
    unsigned short* avhi = akhi + 2 * planeElems;
    unsigned short* arhi = avhi + 2 * planeElems;
    unsigned short* whi  = arhi + 2 * planeElems;

    unsigned short* kb = arhi;
    unsigned short* vb = akhi;
    unsigned short* rb = (unsigned short*)out;
    unsigned short* yhi = avhi;
    float* chend = (float*)whi;

    const int wcBlocks = (C_ * C_ / 4) / 256;           // 4096
    const dim3 wkvGrid(C_ / 512, NCH, B_);

    // 1. fused LN + 3x mix -> bf16 A planes
    ln_mix3_kernel<<<M_, 256, 0, stream>>>(x, ln_w, ln_b, mix_k, mix_v, mix_r,
                                           akhi, avhi, arhi);

    // 2. r projection (sigmoid fused) -> bf16 in d_out
    wconv_kernel<<<wcBlocks, 256, 0, stream>>>(Wr, whi);
    gemm_mfma<true, true><<<256, 512, 0, stream>>>(arhi, whi, nullptr, rb);

    // 3. k projection -> bf16 kb (over Ar region)
    wconv_kernel<<<wcBlocks, 256, 0, stream>>>(Wk, whi);
    gemm_mfma<false, true><<<256, 512, 0, stream>>>(akhi, whi, nullptr, kb);

    // 4. v projection -> bf16 vb (over Ak region)
    wconv_kernel<<<wcBlocks, 256, 0, stream>>>(Wv, whi);
    gemm_mfma<false, true><<<256, 512, 0, stream>>>(avhi, whi, nullptr, vb);

    // 5. WKV chunked scan -> y bf16 plane (over Av region; chend over W region)
    wkv_scan1<<<wkvGrid, 256, 0, stream>>>(kb, time_decay, chend);
    wkv_scan2<<<wkvGrid, 256, 0, stream>>>(kb, vb, rb, time_decay, time_first, chend,
                                           yhi);

    // 6. output projection -> fp32 d_out (wconv overwrites chend after scan2)
    wconv_kernel<<<wcBlocks, 256, 0, stream>>>(Wo, whi);
    gemm_mfma<false, false><<<256, 512, 0, stream>>>(yhi, whi, out, nullptr);
}

// Round 23
// 354.111 us; speedup vs baseline: 1.2332x; 1.0197x over previous
//
#include <hip/hip_runtime.h>
#include <math.h>

// RWKV6 block on MI355X. fp32 problem; GEMMs in pure bf16 MFMA. B=4,T=2048,C=2048.
// R23 = R21 (361 us) + launch-graph fusion, fixed: gemm_proj3 selects
// pointers via switch then makes ONE gemm_body call (single 128KB LDS
// allocation; R22 failed compile with 3 inlined copies). sigmoid is a
// runtime flag (epilogue-only). GEMM inner loop / scans / ln_mix3
// bit-identical to R21.
constexpr int B_ = 4;
constexpr int T_ = 2048;
constexpr int C_ = 2048;
constexpr int M_ = B_ * T_;          // 8192 rows
constexpr float EPS_ = 1e-5f;
constexpr int KSTEPS = C_ / 64;      // 32
constexpr int NCH = 32;              // scan chunks
constexpr int CHL = T_ / NCH;        // 64 steps/chunk

typedef __attribute__((ext_vector_type(8))) short short8;   // bf16x8 MFMA operand
typedef __attribute__((ext_vector_type(4))) float f32x4;    // MFMA acc

__device__ __forceinline__ unsigned short rne_bf16(float x) {
    unsigned u = __float_as_uint(x);
    unsigned r = u + 0x7FFFu + ((u >> 16) & 1u);
    return (unsigned short)(r >> 16);
}
__device__ __forceinline__ float bf16_to_f32(unsigned short h) {
    return __uint_as_float((unsigned)h << 16);
}

// -------- fused LayerNorm (rows m, m-1) + 3x time-mix -> bf16 planes --------
__global__ __launch_bounds__(256) void ln_mix3_kernel(
        const float* __restrict__ x,
        const float* __restrict__ w,
        const float* __restrict__ bias,
        const float* __restrict__ mxk,
        const float* __restrict__ mxv,
        const float* __restrict__ mxr,
        unsigned short* __restrict__ ak,
        unsigned short* __restrict__ av,
        unsigned short* __restrict__ ar) {
    const int m = blockIdx.x;
    const int tid = threadIdx.x;
    const bool hasPrev = (m & (T_ - 1)) != 0;
    const float* xm = x + (size_t)m * C_;

    float4 a0 = ((const float4*)xm)[tid];
    float4 a1 = ((const float4*)xm)[tid + 256];
    float4 p0 = make_float4(0.f, 0.f, 0.f, 0.f), p1 = p0;
    if (hasPrev) {
        p0 = ((const float4*)(xm - C_))[tid];
        p1 = ((const float4*)(xm - C_))[tid + 256];
    }

    float sm = a0.x + a0.y + a0.z + a0.w + a1.x + a1.y + a1.z + a1.w;
    float qm = a0.x*a0.x + a0.y*a0.y + a0.z*a0.z + a0.w*a0.w
             + a1.x*a1.x + a1.y*a1.y + a1.z*a1.z + a1.w*a1.w;
    float sp = p0.x + p0.y + p0.z + p0.w + p1.x + p1.y + p1.z + p1.w;
    float qp = p0.x*p0.x + p0.y*p0.y + p0.z*p0.z + p0.w*p0.w
             + p1.x*p1.x + p1.y*p1.y + p1.z*p1.z + p1.w*p1.w;

    #pragma unroll
    for (int off = 32; off > 0; off >>= 1) {
        sm += __shfl_down(sm, off, 64);
        qm += __shfl_down(qm, off, 64);
        sp += __shfl_down(sp, off, 64);
        qp += __shfl_down(qp, off, 64);
    }
    __shared__ float red[20];
    const int wid = tid >> 6, lane = tid & 63;
    if (lane == 0) {
        red[wid * 4 + 0] = sm; red[wid * 4 + 1] = qm;
        red[wid * 4 + 2] = sp; red[wid * 4 + 3] = qp;
    }
    __syncthreads();
    if (tid == 0) {
        float tsm = 0.f, tqm = 0.f, tsp = 0.f, tqp = 0.f;
        #pragma unroll
        for (int i = 0; i < 4; ++i) {
            tsm += red[i * 4 + 0]; tqm += red[i * 4 + 1];
            tsp += red[i * 4 + 2]; tqp += red[i * 4 + 3];
        }
        const float mum = tsm / (float)C_;
        const float varm = tqm / (float)C_ - mum * mum;
        const float mup = tsp / (float)C_;
        const float varp = tqp / (float)C_ - mup * mup;
        red[16] = mum; red[17] = rsqrtf(varm + EPS_);
        red[18] = mup; red[19] = rsqrtf(varp + EPS_);
    }
    __syncthreads();
    const float mum = red[16], rsm = red[17];
    const float mup = red[18], rsp = red[19];

    float4 w0 = ((const float4*)w)[tid];
    float4 w1 = ((const float4*)w)[tid + 256];
    float4 b0 = ((const float4*)bias)[tid];
    float4 b1 = ((const float4*)bias)[tid + 256];

    const float avv[8] = {a0.x, a0.y, a0.z, a0.w, a1.x, a1.y, a1.z, a1.w};
    const float pvv[8] = {p0.x, p0.y, p0.z, p0.w, p1.x, p1.y, p1.z, p1.w};
    const float wvv[8] = {w0.x, w0.y, w0.z, w0.w, w1.x, w1.y, w1.z, w1.w};
    const float bvv[8] = {b0.x, b0.y, b0.z, b0.w, b1.x, b1.y, b1.z, b1.w};

    float lm[8], lp[8];
    #pragma unroll
    for (int j = 0; j < 8; ++j) {
        lm[j] = (avv[j] - mum) * rsm * wvv[j] + bvv[j];
        lp[j] = hasPrev ? (pvv[j] - mup) * rsp * wvv[j] + bvv[j] : 0.f;  // prev=0 at t=0
    }

    const size_t rowbase = (size_t)m * C_;
    auto emit = [&](const float* __restrict__ mx, unsigned short* __restrict__ hi) {
        float4 m0 = ((const float4*)mx)[tid];
        float4 m1 = ((const float4*)mx)[tid + 256];
        const float mm[8] = {m0.x, m0.y, m0.z, m0.w, m1.x, m1.y, m1.z, m1.w};
        ushort4 h[2];
        #pragma unroll
        for (int half = 0; half < 2; ++half) {
            unsigned short hh[4];
            #pragma unroll
            for (int j = 0; j < 4; ++j) {
                const int c = half * 4 + j;
                hh[j] = rne_bf16(lp[c] + (lm[c] - lp[c]) * mm[c]);
            }
            h[half].x = hh[0]; h[half].y = hh[1]; h[half].z = hh[2]; h[half].w = hh[3];
        }
        ((ushort4*)(hi + rowbase))[tid] = h[0];
        ((ushort4*)(hi + rowbase))[tid + 256] = h[1];
    };
    emit(mxk, ak);
    emit(mxv, av);
    emit(mxr, ar);
}

// ---------------- 4x W fp32 -> bf16 planes, one dispatch ----------------
__global__ __launch_bounds__(256) void wconv4_kernel(const float* __restrict__ W0,
                                                     const float* __restrict__ W1,
                                                     const float* __restrict__ W2,
                                                     const float* __restrict__ W3,
                                                     unsigned short* __restrict__ h0,
                                                     unsigned short* __restrict__ h1,
                                                     unsigned short* __restrict__ h2,
                                                     unsigned short* __restrict__ h3) {
    const int i = blockIdx.x * 256 + threadIdx.x;   // over C_*C_/4 float4s
    const float* W;
    unsigned short* hi;
    switch (blockIdx.y) {
        case 0:  W = W0; hi = h0; break;
        case 1:  W = W1; hi = h1; break;
        case 2:  W = W2; hi = h2; break;
        default: W = W3; hi = h3; break;
    }
    float4 w = ((const float4*)W)[i];
    ushort4 h;
    h.x = rne_bf16(w.x);
    h.y = rne_bf16(w.y);
    h.z = rne_bf16(w.z);
    h.w = rne_bf16(w.w);
    ((ushort4*)hi)[i] = h;
}

// ---------------- MFMA GEMM body: Y[m,n] = sum_k A[m,k] * W[n,k], bf16 ----
// 256x256 tile, BK=64, 512 threads (8 waves, 2Mx4N). 128KB LDS double-buffer;
// per region 256 rows x 8 slots of 16B, phys slot = s ^ (row&7); linear-dest
// global_load_lds with pre-swizzled per-lane global source (8 issues/thr/tile).
// 2 phases per K-step (one mi-quad x 2 k-subtiles = 32 MFMA each), counted
// vmcnt(4), setprio. R13/R21 structure verbatim. sig is a runtime flag
// (epilogue-only) so callers can make exactly ONE call (one LDS alloc).
template <bool OUTBF16>
__device__ __forceinline__ void gemm_body(const unsigned short* __restrict__ Ahi,
                                          const unsigned short* __restrict__ Whi,
                                          float* __restrict__ Yf,
                                          unsigned short* __restrict__ Yh,
                                          int bid, bool sig) {
    __shared__ unsigned short lds[2][2][256 * 64];

    const int tid = threadIdx.x;
    const int lane = tid & 63;
    const int wid = tid >> 6;          // 0..7
    const int wr = wid >> 2;           // 0..1  (M half: 128 rows)
    const int wcn = wid & 3;           // 0..3  (N quarter: 64 cols)

    // XCD-chunked block swizzle: 256 blocks, 8 XCDs, 32/XCD
    const int swz = (bid & 7) * 32 + (bid >> 3);
    const int m0 = (swz >> 3) * 256;
    const int n0 = (swz & 7) * 256;

    const unsigned short* gA[4];
    const unsigned short* gB[4];
    #pragma unroll
    for (int j = 0; j < 4; ++j) {
        const int ci = j * 512 + tid;
        const int r = ci >> 3, p = ci & 7;
        const int s = p ^ (r & 7);      // logical k-chunk 0..7 within BK=64
        gA[j] = Ahi + (size_t)(m0 + r) * C_ + s * 8;
        gB[j] = Whi + (size_t)(n0 + r) * C_ + s * 8;
    }
    const int stage_off = wid * 512;

    const int fr = lane & 15;
    const int kg = lane >> 4;
    const int pS0 = (kg + 0) ^ (fr & 7);   // k-subtile 0 (k 0..31)
    const int pS1 = (kg + 4) ^ (fr & 7);   // k-subtile 1 (k 32..63)
    const int baseA0 = (wr * 128 + fr) * 64 + pS0 * 8;
    const int baseA1 = (wr * 128 + fr) * 64 + pS1 * 8;
    const int baseB0 = (wcn * 64 + fr) * 64 + pS0 * 8;
    const int baseB1 = (wcn * 64 + fr) * 64 + pS1 * 8;

    f32x4 acc[8][4] = {};

    auto ISSUE = [&](int buf, int t, int j) {
        const int ko = t * 64;
        __builtin_amdgcn_global_load_lds(
            (const __attribute__((address_space(1))) unsigned int*)(gA[j] + ko),
            (__attribute__((address_space(3))) unsigned int*)&lds[buf][0][j * 4096 + stage_off],
            16, 0, 0);
        __builtin_amdgcn_global_load_lds(
            (const __attribute__((address_space(1))) unsigned int*)(gB[j] + ko),
            (__attribute__((address_space(3))) unsigned int*)&lds[buf][1][j * 4096 + stage_off],
            16, 0, 0);
    };

    auto MFMA_QUAD = [&](int mi0, const short8* a0, const short8* a1,
                         const short8* b0, const short8* b1) {
        #pragma unroll
        for (int ni = 0; ni < 4; ++ni)
            #pragma unroll
            for (int q = 0; q < 4; ++q)
                acc[mi0 + q][ni] = __builtin_amdgcn_mfma_f32_16x16x32_bf16(a0[q], b0[ni], acc[mi0 + q][ni], 0, 0, 0);
        #pragma unroll
        for (int ni = 0; ni < 4; ++ni)
            #pragma unroll
            for (int q = 0; q < 4; ++q)
                acc[mi0 + q][ni] = __builtin_amdgcn_mfma_f32_16x16x32_bf16(a1[q], b1[ni], acc[mi0 + q][ni], 0, 0, 0);
    };

    // prologue: stage tile 0 (8 loads/thread)
    #pragma unroll
    for (int j = 0; j < 4; ++j) ISSUE(0, 0, j);

    for (int t = 0; t < KSTEPS; ++t) {
        const int cur = t & 1, nxt = cur ^ 1;
        const bool last = (t == KSTEPS - 1);
        const unsigned short* LA = lds[cur][0];
        const unsigned short* LB = lds[cur][1];

        short8 b0[4], b1[4];

        // ---------- phase 0 (mi 0-3): validate buf cur, read B frags ----------
        if (!last) {
            ISSUE(nxt, t + 1, 0);
            ISSUE(nxt, t + 1, 1);
            asm volatile("s_waitcnt vmcnt(4)" ::: "memory");  // tile t's 8 done
        } else {
            asm volatile("s_waitcnt vmcnt(0)" ::: "memory");
        }
        __builtin_amdgcn_s_barrier();
        #pragma unroll
        for (int ni = 0; ni < 4; ++ni) {
            b0[ni] = *(const short8*)&LB[baseB0 + ni * 1024];
            b1[ni] = *(const short8*)&LB[baseB1 + ni * 1024];
        }
        {
            short8 a0[4], a1[4];
            #pragma unroll
            for (int q = 0; q < 4; ++q) {
                a0[q] = *(const short8*)&LA[baseA0 + q * 1024];
                a1[q] = *(const short8*)&LA[baseA1 + q * 1024];
            }
            asm volatile("s_waitcnt lgkmcnt(0)" ::: "memory");
            __builtin_amdgcn_s_setprio(1);
            MFMA_QUAD(0, a0, a1, b0, b1);
            __builtin_amdgcn_s_setprio(0);
        }
        __builtin_amdgcn_s_barrier();

        // ---------- phase 1 (mi 4-7) ----------
        {
            short8 a0[4], a1[4];
            #pragma unroll
            for (int q = 0; q < 4; ++q) {
                a0[q] = *(const short8*)&LA[baseA0 + (4 + q) * 1024];
                a1[q] = *(const short8*)&LA[baseA1 + (4 + q) * 1024];
            }
            if (!last) {
                ISSUE(nxt, t + 1, 2);
                ISSUE(nxt, t + 1, 3);
            }
            __builtin_amdgcn_s_barrier();
            asm volatile("s_waitcnt lgkmcnt(0)" ::: "memory");
            __builtin_amdgcn_s_setprio(1);
            MFMA_QUAD(4, a0, a1, b0, b1);
            __builtin_amdgcn_s_setprio(0);
            __builtin_amdgcn_s_barrier();
        }
    }

    // ---- epilogue: C/D layout col=lane&15, row=(lane>>4)*4+reg ----
    const int orow = m0 + wr * 128 + (lane >> 4) * 4;
    const int ocol = n0 + wcn * 64 + fr;
    #pragma unroll
    for (int mi = 0; mi < 8; ++mi)
        #pragma unroll
        for (int ni = 0; ni < 4; ++ni)
            #pragma unroll
            for (int rr = 0; rr < 4; ++rr) {
                float v = acc[mi][ni][rr];
                if (sig) v = 1.f / (1.f + expf(-v));
                const size_t idx = (size_t)(orow + mi * 16 + rr) * C_ + ocol + ni * 16;
                if (OUTBF16) Yh[idx] = rne_bf16(v);
                else         Yf[idx] = v;
            }
}

// Merged r/k/v projection GEMM: 768 blocks; proj = bid>>8 (0=r sigmoid, 1=k, 2=v).
// Pointer selection via switch, then ONE gemm_body call (single LDS alloc).
__global__ __launch_bounds__(512, 2) void gemm_proj3(const unsigned short* __restrict__ ar,
                                                     const unsigned short* __restrict__ ak,
                                                     const unsigned short* __restrict__ av,
                                                     const unsigned short* __restrict__ wr,
                                                     const unsigned short* __restrict__ wk,
                                                     const unsigned short* __restrict__ wv,
                                                     unsigned short* __restrict__ rb,
                                                     unsigned short* __restrict__ kb,
                                                     unsigned short* __restrict__ vb) {
    const int bid = blockIdx.x;
    const int proj = bid >> 8;
    const int inner = bid & 255;
    const unsigned short* A;
    const unsigned short* W;
    unsigned short* Y;
    bool sig;
    if (proj == 0)      { A = ar; W = wr; Y = rb; sig = true;  }
    else if (proj == 1) { A = ak; W = wk; Y = kb; sig = false; }
    else                { A = av; W = wv; Y = vb; sig = false; }
    gemm_body<true>(A, W, nullptr, Y, inner, sig);
}

// Output projection GEMM: fp32 output
__global__ __launch_bounds__(512, 2) void gemm_out(const unsigned short* __restrict__ A,
                                                   const unsigned short* __restrict__ W,
                                                   float* __restrict__ Y) {
    gemm_body<false>(A, W, Y, nullptr, blockIdx.x, false);
}

// ---------------- WKV chunked scan, pass 1: per-chunk local end state ----
__global__ __launch_bounds__(256) void wkv_scan1(const unsigned short* __restrict__ k,
                                                 const float* __restrict__ time_decay,
                                                 float* __restrict__ chend) {
    const int c0 = (blockIdx.x * 256 + threadIdx.x) * 2;
    const int j = blockIdx.y;
    const int b = blockIdx.z;
    const float2 td = *(const float2*)&time_decay[c0];
    const float d0 = 1.f / (1.f + expf(-td.x));
    const float d1 = 1.f / (1.f + expf(-td.y));
    size_t base = ((size_t)b * T_ + (size_t)j * CHL) * C_ + c0;
    float s0 = 0.f, s1 = 0.f;
    #pragma unroll 8
    for (int t = 0; t < CHL; ++t) {
        const ushort2 kt = *(const ushort2*)&k[base];
        s0 = s0 * d0 + bf16_to_f32(kt.x);
        s1 = s1 * d1 + bf16_to_f32(kt.y);
        base += C_;
    }
    *(float2*)&chend[((size_t)b * NCH + j) * C_ + c0] = make_float2(s0, s1);
}

// ---------------- WKV chunked scan, pass 2: carry-in + rescan + fuse -----
__global__ __launch_bounds__(256) void wkv_scan2(const unsigned short* __restrict__ k,
                                                 const unsigned short* __restrict__ v,
                                                 const unsigned short* __restrict__ r,
                                                 const float* __restrict__ time_decay,
                                                 const float* __restrict__ time_first,
                                                 const float* __restrict__ chend,
                                                 unsigned short* __restrict__ yhi) {
    const int c0 = (blockIdx.x * 256 + threadIdx.x) * 2;
    const int j = blockIdx.y;
    const int b = blockIdx.z;
    const float2 td = *(const float2*)&time_decay[c0];
    const float2 tf = *(const float2*)&time_first[c0];
    const float d0 = 1.f / (1.f + expf(-td.x));
    const float d1 = 1.f / (1.f + expf(-td.y));
    const float f0 = expf(tf.x);
    const float f1 = expf(tf.y);

    float dL0 = d0, dL1 = d1;           // d^CHL, CHL=64 -> 6 squarings
    #pragma unroll
    for (int i = 0; i < 6; ++i) { dL0 *= dL0; dL1 *= dL1; }

    float s0 = 0.f, s1 = 0.f;
    for (int i = 0; i < j; ++i) {
        const float2 e = *(const float2*)&chend[((size_t)b * NCH + i) * C_ + c0];
        s0 = s0 * dL0 + e.x;
        s1 = s1 * dL1 + e.y;
    }

    size_t base = ((size_t)b * T_ + (size_t)j * CHL) * C_ + c0;
    #pragma unroll 4
    for (int t = 0; t < CHL; ++t) {
        const ushort2 kt = *(const ushort2*)&k[base];
        const ushort2 vt = *(const ushort2*)&v[base];
        const ushort2 rt = *(const ushort2*)&r[base];
        const float k0 = bf16_to_f32(kt.x), k1 = bf16_to_f32(kt.y);
        s0 = s0 * d0 + k0;
        s1 = s1 * d1 + k1;
        const float y0 = bf16_to_f32(rt.x) * ((s0 * f0 + k0) * bf16_to_f32(vt.x));
        const float y1 = bf16_to_f32(rt.y) * ((s1 * f1 + k1) * bf16_to_f32(vt.y));
        ushort2 ph; ph.x = rne_bf16(y0); ph.y = rne_bf16(y1);
        *(ushort2*)&yhi[base] = ph;
        base += C_;
    }
}

// ---------------- launch ----------------
extern "C" void kernel_launch(void* const* d_in, const int* in_sizes, int n_in,
                              void* d_out, int out_size, void* d_ws, size_t ws_size,
                              hipStream_t stream) {
    const float* x          = (const float*)d_in[0];
    const float* ln_w       = (const float*)d_in[1];
    const float* ln_b       = (const float*)d_in[2];
    const float* mix_k      = (const float*)d_in[3];
    const float* mix_v      = (const float*)d_in[4];
    const float* mix_r      = (const float*)d_in[5];
    const float* time_decay = (const float*)d_in[6];
    const float* time_first = (const float*)d_in[7];
    const float* Wk         = (const float*)d_in[8];
    const float* Wv         = (const float*)d_in[9];
    const float* Wr         = (const float*)d_in[10];
    const float* Wo         = (const float*)d_in[11];
    float* out = (float*)d_out;

    // ws (201.3 MB): ak | av | ar | kb | vb (bf16 planes, 33.5 MB each)
    //              | wr | wk | wv | wo (bf16 W planes, 8.4 MB each)
    // Merged GEMM: no aliasing among its in/outputs. Post-merge reuse:
    // yhi -> ak (dead), chend -> wr (dead); rb -> d_out bf16 (consumed by
    // scan2 before gemm_out overwrites d_out with fp32).
    const size_t P = (size_t)M_ * C_;
    unsigned short* ak = (unsigned short*)d_ws;
    unsigned short* av = ak + P;
    unsigned short* ar = av + P;
    unsigned short* kb = ar + P;
    unsigned short* vb = kb + P;
    unsigned short* wr = vb + P;
    unsigned short* wk = wr + P / 4;
    unsigned short* wv = wk + P / 4;
    unsigned short* wo = wv + P / 4;

    unsigned short* rb = (unsigned short*)out;
    unsigned short* yhi = ak;
    float* chend = (float*)wr;

    const dim3 wcGrid((C_ * C_ / 4) / 256, 4);          // 4096 x 4
    const dim3 wkvGrid(C_ / 512, NCH, B_);

    // 1. all four W planes in one dispatch
    wconv4_kernel<<<wcGrid, 256, 0, stream>>>(Wr, Wk, Wv, Wo, wr, wk, wv, wo);

    // 2. fused LN + 3x mix -> bf16 A planes
    ln_mix3_kernel<<<M_, 256, 0, stream>>>(x, ln_w, ln_b, mix_k, mix_v, mix_r,
                                           ak, av, ar);

    // 3. merged r/k/v projection GEMM (768 blocks; r has sigmoid fused)
    gemm_proj3<<<768, 512, 0, stream>>>(ar, ak, av, wr, wk, wv, rb, kb, vb);

    // 4. WKV chunked scan -> y bf16 plane (yhi over ak; chend over wr)
    wkv_scan1<<<wkvGrid, 256, 0, stream>>>(kb, time_decay, chend);
    wkv_scan2<<<wkvGrid, 256, 0, stream>>>(kb, vb, rb, time_decay, time_first, chend,
                                           yhi);

    // 5. output projection -> fp32 d_out
    gemm_out<<<256, 512, 0, stream>>>(yhi, wo, out);
}

// Round 24
// 350.849 us; speedup vs baseline: 1.2447x; 1.0093x over previous
//
#include <hip/hip_runtime.h>
#include <math.h>

// RWKV6 block on MI355X. fp32 problem; GEMMs in pure bf16 MFMA. B=4,T=2048,C=2048.
// R24 = R23 (354 us) + prep fusion: wconv4 and ln_mix3 merged into ONE
// dispatch (independent memory-bound work; per-block path select).
// GEMM body / scans bit-identical to R23.
constexpr int B_ = 4;
constexpr int T_ = 2048;
constexpr int C_ = 2048;
constexpr int M_ = B_ * T_;          // 8192 rows
constexpr float EPS_ = 1e-5f;
constexpr int KSTEPS = C_ / 64;      // 32
constexpr int NCH = 32;              // scan chunks
constexpr int CHL = T_ / NCH;        // 64 steps/chunk

typedef __attribute__((ext_vector_type(8))) short short8;   // bf16x8 MFMA operand
typedef __attribute__((ext_vector_type(4))) float f32x4;    // MFMA acc

__device__ __forceinline__ unsigned short rne_bf16(float x) {
    unsigned u = __float_as_uint(x);
    unsigned r = u + 0x7FFFu + ((u >> 16) & 1u);
    return (unsigned short)(r >> 16);
}
__device__ __forceinline__ float bf16_to_f32(unsigned short h) {
    return __uint_as_float((unsigned)h << 16);
}

// -------- fused prep: [bid < 16384] W fp32->bf16 plane copy (4 planes)
//          [bid >= 16384] LayerNorm(rows m,m-1) + 3x time-mix -> bf16 planes
__global__ __launch_bounds__(256) void prep_kernel(
        const float* __restrict__ x,
        const float* __restrict__ w,
        const float* __restrict__ bias,
        const float* __restrict__ mxk,
        const float* __restrict__ mxv,
        const float* __restrict__ mxr,
        const float* __restrict__ W0, const float* __restrict__ W1,
        const float* __restrict__ W2, const float* __restrict__ W3,
        unsigned short* __restrict__ h0, unsigned short* __restrict__ h1,
        unsigned short* __restrict__ h2, unsigned short* __restrict__ h3,
        unsigned short* __restrict__ ak,
        unsigned short* __restrict__ av,
        unsigned short* __restrict__ ar) {
    const int tid = threadIdx.x;

    if (blockIdx.x < 16384) {
        // ---- W conversion: plane p = bid>>12, chunk = bid&4095 ----
        const int p = blockIdx.x >> 12;
        const int i = (blockIdx.x & 4095) * 256 + tid;   // over C_*C_/4 float4s
        const float* W;
        unsigned short* hi;
        switch (p) {
            case 0:  W = W0; hi = h0; break;
            case 1:  W = W1; hi = h1; break;
            case 2:  W = W2; hi = h2; break;
            default: W = W3; hi = h3; break;
        }
        float4 wv4 = ((const float4*)W)[i];
        ushort4 h;
        h.x = rne_bf16(wv4.x);
        h.y = rne_bf16(wv4.y);
        h.z = rne_bf16(wv4.z);
        h.w = rne_bf16(wv4.w);
        ((ushort4*)hi)[i] = h;
        return;
    }

    // ---- LN + mix path ----
    const int m = blockIdx.x - 16384;
    const bool hasPrev = (m & (T_ - 1)) != 0;
    const float* xm = x + (size_t)m * C_;

    float4 a0 = ((const float4*)xm)[tid];
    float4 a1 = ((const float4*)xm)[tid + 256];
    float4 p0 = make_float4(0.f, 0.f, 0.f, 0.f), p1 = p0;
    if (hasPrev) {
        p0 = ((const float4*)(xm - C_))[tid];
        p1 = ((const float4*)(xm - C_))[tid + 256];
    }

    float sm = a0.x + a0.y + a0.z + a0.w + a1.x + a1.y + a1.z + a1.w;
    float qm = a0.x*a0.x + a0.y*a0.y + a0.z*a0.z + a0.w*a0.w
             + a1.x*a1.x + a1.y*a1.y + a1.z*a1.z + a1.w*a1.w;
    float sp = p0.x + p0.y + p0.z + p0.w + p1.x + p1.y + p1.z + p1.w;
    float qp = p0.x*p0.x + p0.y*p0.y + p0.z*p0.z + p0.w*p0.w
             + p1.x*p1.x + p1.y*p1.y + p1.z*p1.z + p1.w*p1.w;

    #pragma unroll
    for (int off = 32; off > 0; off >>= 1) {
        sm += __shfl_down(sm, off, 64);
        qm += __shfl_down(qm, off, 64);
        sp += __shfl_down(sp, off, 64);
        qp += __shfl_down(qp, off, 64);
    }
    __shared__ float red[20];
    const int wid = tid >> 6, lane = tid & 63;
    if (lane == 0) {
        red[wid * 4 + 0] = sm; red[wid * 4 + 1] = qm;
        red[wid * 4 + 2] = sp; red[wid * 4 + 3] = qp;
    }
    __syncthreads();
    if (tid == 0) {
        float tsm = 0.f, tqm = 0.f, tsp = 0.f, tqp = 0.f;
        #pragma unroll
        for (int i = 0; i < 4; ++i) {
            tsm += red[i * 4 + 0]; tqm += red[i * 4 + 1];
            tsp += red[i * 4 + 2]; tqp += red[i * 4 + 3];
        }
        const float mum = tsm / (float)C_;
        const float varm = tqm / (float)C_ - mum * mum;
        const float mup = tsp / (float)C_;
        const float varp = tqp / (float)C_ - mup * mup;
        red[16] = mum; red[17] = rsqrtf(varm + EPS_);
        red[18] = mup; red[19] = rsqrtf(varp + EPS_);
    }
    __syncthreads();
    const float mum = red[16], rsm = red[17];
    const float mup = red[18], rsp = red[19];

    float4 w0 = ((const float4*)w)[tid];
    float4 w1 = ((const float4*)w)[tid + 256];
    float4 b0 = ((const float4*)bias)[tid];
    float4 b1 = ((const float4*)bias)[tid + 256];

    const float avv[8] = {a0.x, a0.y, a0.z, a0.w, a1.x, a1.y, a1.z, a1.w};
    const float pvv[8] = {p0.x, p0.y, p0.z, p0.w, p1.x, p1.y, p1.z, p1.w};
    const float wvv[8] = {w0.x, w0.y, w0.z, w0.w, w1.x, w1.y, w1.z, w1.w};
    const float bvv[8] = {b0.x, b0.y, b0.z, b0.w, b1.x, b1.y, b1.z, b1.w};

    float lm[8], lp[8];
    #pragma unroll
    for (int j = 0; j < 8; ++j) {
        lm[j] = (avv[j] - mum) * rsm * wvv[j] + bvv[j];
        lp[j] = hasPrev ? (pvv[j] - mup) * rsp * wvv[j] + bvv[j] : 0.f;  // prev=0 at t=0
    }

    const size_t rowbase = (size_t)m * C_;
    auto emit = [&](const float* __restrict__ mx, unsigned short* __restrict__ hi) {
        float4 m0 = ((const float4*)mx)[tid];
        float4 m1 = ((const float4*)mx)[tid + 256];
        const float mm[8] = {m0.x, m0.y, m0.z, m0.w, m1.x, m1.y, m1.z, m1.w};
        ushort4 h[2];
        #pragma unroll
        for (int half = 0; half < 2; ++half) {
            unsigned short hh[4];
            #pragma unroll
            for (int j = 0; j < 4; ++j) {
                const int c = half * 4 + j;
                hh[j] = rne_bf16(lp[c] + (lm[c] - lp[c]) * mm[c]);
            }
            h[half].x = hh[0]; h[half].y = hh[1]; h[half].z = hh[2]; h[half].w = hh[3];
        }
        ((ushort4*)(hi + rowbase))[tid] = h[0];
        ((ushort4*)(hi + rowbase))[tid + 256] = h[1];
    };
    emit(mxk, ak);
    emit(mxv, av);
    emit(mxr, ar);
}

// ---------------- MFMA GEMM body: Y[m,n] = sum_k A[m,k] * W[n,k], bf16 ----
// 256x256 tile, BK=64, 512 threads (8 waves, 2Mx4N). 128KB LDS double-buffer;
// per region 256 rows x 8 slots of 16B, phys slot = s ^ (row&7); linear-dest
// global_load_lds with pre-swizzled per-lane global source (8 issues/thr/tile).
// 2 phases per K-step (one mi-quad x 2 k-subtiles = 32 MFMA each), counted
// vmcnt(4), setprio. sig is a runtime flag (epilogue-only) so callers make
// exactly ONE call (one LDS alloc).
template <bool OUTBF16>
__device__ __forceinline__ void gemm_body(const unsigned short* __restrict__ Ahi,
                                          const unsigned short* __restrict__ Whi,
                                          float* __restrict__ Yf,
                                          unsigned short* __restrict__ Yh,
                                          int bid, bool sig) {
    __shared__ unsigned short lds[2][2][256 * 64];

    const int tid = threadIdx.x;
    const int lane = tid & 63;
    const int wid = tid >> 6;          // 0..7
    const int wr = wid >> 2;           // 0..1  (M half: 128 rows)
    const int wcn = wid & 3;           // 0..3  (N quarter: 64 cols)

    // XCD-chunked block swizzle: 256 blocks, 8 XCDs, 32/XCD
    const int swz = (bid & 7) * 32 + (bid >> 3);
    const int m0 = (swz >> 3) * 256;
    const int n0 = (swz & 7) * 256;

    const unsigned short* gA[4];
    const unsigned short* gB[4];
    #pragma unroll
    for (int j = 0; j < 4; ++j) {
        const int ci = j * 512 + tid;
        const int r = ci >> 3, p = ci & 7;
        const int s = p ^ (r & 7);      // logical k-chunk 0..7 within BK=64
        gA[j] = Ahi + (size_t)(m0 + r) * C_ + s * 8;
        gB[j] = Whi + (size_t)(n0 + r) * C_ + s * 8;
    }
    const int stage_off = wid * 512;

    const int fr = lane & 15;
    const int kg = lane >> 4;
    const int pS0 = (kg + 0) ^ (fr & 7);   // k-subtile 0 (k 0..31)
    const int pS1 = (kg + 4) ^ (fr & 7);   // k-subtile 1 (k 32..63)
    const int baseA0 = (wr * 128 + fr) * 64 + pS0 * 8;
    const int baseA1 = (wr * 128 + fr) * 64 + pS1 * 8;
    const int baseB0 = (wcn * 64 + fr) * 64 + pS0 * 8;
    const int baseB1 = (wcn * 64 + fr) * 64 + pS1 * 8;

    f32x4 acc[8][4] = {};

    auto ISSUE = [&](int buf, int t, int j) {
        const int ko = t * 64;
        __builtin_amdgcn_global_load_lds(
            (const __attribute__((address_space(1))) unsigned int*)(gA[j] + ko),
            (__attribute__((address_space(3))) unsigned int*)&lds[buf][0][j * 4096 + stage_off],
            16, 0, 0);
        __builtin_amdgcn_global_load_lds(
            (const __attribute__((address_space(1))) unsigned int*)(gB[j] + ko),
            (__attribute__((address_space(3))) unsigned int*)&lds[buf][1][j * 4096 + stage_off],
            16, 0, 0);
    };

    auto MFMA_QUAD = [&](int mi0, const short8* a0, const short8* a1,
                         const short8* b0, const short8* b1) {
        #pragma unroll
        for (int ni = 0; ni < 4; ++ni)
            #pragma unroll
            for (int q = 0; q < 4; ++q)
                acc[mi0 + q][ni] = __builtin_amdgcn_mfma_f32_16x16x32_bf16(a0[q], b0[ni], acc[mi0 + q][ni], 0, 0, 0);
        #pragma unroll
        for (int ni = 0; ni < 4; ++ni)
            #pragma unroll
            for (int q = 0; q < 4; ++q)
                acc[mi0 + q][ni] = __builtin_amdgcn_mfma_f32_16x16x32_bf16(a1[q], b1[ni], acc[mi0 + q][ni], 0, 0, 0);
    };

    // prologue: stage tile 0 (8 loads/thread)
    #pragma unroll
    for (int j = 0; j < 4; ++j) ISSUE(0, 0, j);

    for (int t = 0; t < KSTEPS; ++t) {
        const int cur = t & 1, nxt = cur ^ 1;
        const bool last = (t == KSTEPS - 1);
        const unsigned short* LA = lds[cur][0];
        const unsigned short* LB = lds[cur][1];

        short8 b0[4], b1[4];

        // ---------- phase 0 (mi 0-3): validate buf cur, read B frags ----------
        if (!last) {
            ISSUE(nxt, t + 1, 0);
            ISSUE(nxt, t + 1, 1);
            asm volatile("s_waitcnt vmcnt(4)" ::: "memory");  // tile t's 8 done
        } else {
            asm volatile("s_waitcnt vmcnt(0)" ::: "memory");
        }
        __builtin_amdgcn_s_barrier();
        #pragma unroll
        for (int ni = 0; ni < 4; ++ni) {
            b0[ni] = *(const short8*)&LB[baseB0 + ni * 1024];
            b1[ni] = *(const short8*)&LB[baseB1 + ni * 1024];
        }
        {
            short8 a0[4], a1[4];
            #pragma unroll
            for (int q = 0; q < 4; ++q) {
                a0[q] = *(const short8*)&LA[baseA0 + q * 1024];
                a1[q] = *(const short8*)&LA[baseA1 + q * 1024];
            }
            asm volatile("s_waitcnt lgkmcnt(0)" ::: "memory");
            __builtin_amdgcn_s_setprio(1);
            MFMA_QUAD(0, a0, a1, b0, b1);
            __builtin_amdgcn_s_setprio(0);
        }
        __builtin_amdgcn_s_barrier();

        // ---------- phase 1 (mi 4-7) ----------
        {
            short8 a0[4], a1[4];
            #pragma unroll
            for (int q = 0; q < 4; ++q) {
                a0[q] = *(const short8*)&LA[baseA0 + (4 + q) * 1024];
                a1[q] = *(const short8*)&LA[baseA1 + (4 + q) * 1024];
            }
            if (!last) {
                ISSUE(nxt, t + 1, 2);
                ISSUE(nxt, t + 1, 3);
            }
            __builtin_amdgcn_s_barrier();
            asm volatile("s_waitcnt lgkmcnt(0)" ::: "memory");
            __builtin_amdgcn_s_setprio(1);
            MFMA_QUAD(4, a0, a1, b0, b1);
            __builtin_amdgcn_s_setprio(0);
            __builtin_amdgcn_s_barrier();
        }
    }

    // ---- epilogue: C/D layout col=lane&15, row=(lane>>4)*4+reg ----
    const int orow = m0 + wr * 128 + (lane >> 4) * 4;
    const int ocol = n0 + wcn * 64 + fr;
    #pragma unroll
    for (int mi = 0; mi < 8; ++mi)
        #pragma unroll
        for (int ni = 0; ni < 4; ++ni)
            #pragma unroll
            for (int rr = 0; rr < 4; ++rr) {
                float v = acc[mi][ni][rr];
                if (sig) v = 1.f / (1.f + expf(-v));
                const size_t idx = (size_t)(orow + mi * 16 + rr) * C_ + ocol + ni * 16;
                if (OUTBF16) Yh[idx] = rne_bf16(v);
                else         Yf[idx] = v;
            }
}

// Merged r/k/v projection GEMM: 768 blocks; proj = bid>>8 (0=r sigmoid, 1=k, 2=v).
__global__ __launch_bounds__(512, 2) void gemm_proj3(const unsigned short* __restrict__ ar,
                                                     const unsigned short* __restrict__ ak,
                                                     const unsigned short* __restrict__ av,
                                                     const unsigned short* __restrict__ wr,
                                                     const unsigned short* __restrict__ wk,
                                                     const unsigned short* __restrict__ wv,
                                                     unsigned short* __restrict__ rb,
                                                     unsigned short* __restrict__ kb,
                                                     unsigned short* __restrict__ vb) {
    const int bid = blockIdx.x;
    const int proj = bid >> 8;
    const int inner = bid & 255;
    const unsigned short* A;
    const unsigned short* W;
    unsigned short* Y;
    bool sig;
    if (proj == 0)      { A = ar; W = wr; Y = rb; sig = true;  }
    else if (proj == 1) { A = ak; W = wk; Y = kb; sig = false; }
    else                { A = av; W = wv; Y = vb; sig = false; }
    gemm_body<true>(A, W, nullptr, Y, inner, sig);
}

// Output projection GEMM: fp32 output
__global__ __launch_bounds__(512, 2) void gemm_out(const unsigned short* __restrict__ A,
                                                   const unsigned short* __restrict__ W,
                                                   float* __restrict__ Y) {
    gemm_body<false>(A, W, Y, nullptr, blockIdx.x, false);
}

// ---------------- WKV chunked scan, pass 1: per-chunk local end state ----
__global__ __launch_bounds__(256) void wkv_scan1(const unsigned short* __restrict__ k,
                                                 const float* __restrict__ time_decay,
                                                 float* __restrict__ chend) {
    const int c0 = (blockIdx.x * 256 + threadIdx.x) * 2;
    const int j = blockIdx.y;
    const int b = blockIdx.z;
    const float2 td = *(const float2*)&time_decay[c0];
    const float d0 = 1.f / (1.f + expf(-td.x));
    const float d1 = 1.f / (1.f + expf(-td.y));
    size_t base = ((size_t)b * T_ + (size_t)j * CHL) * C_ + c0;
    float s0 = 0.f, s1 = 0.f;
    #pragma unroll 8
    for (int t = 0; t < CHL; ++t) {
        const ushort2 kt = *(const ushort2*)&k[base];
        s0 = s0 * d0 + bf16_to_f32(kt.x);
        s1 = s1 * d1 + bf16_to_f32(kt.y);
        base += C_;
    }
    *(float2*)&chend[((size_t)b * NCH + j) * C_ + c0] = make_float2(s0, s1);
}

// ---------------- WKV chunked scan, pass 2: carry-in + rescan + fuse -----
__global__ __launch_bounds__(256) void wkv_scan2(const unsigned short* __restrict__ k,
                                                 const unsigned short* __restrict__ v,
                                                 const unsigned short* __restrict__ r,
                                                 const float* __restrict__ time_decay,
                                                 const float* __restrict__ time_first,
                                                 const float* __restrict__ chend,
                                                 unsigned short* __restrict__ yhi) {
    const int c0 = (blockIdx.x * 256 + threadIdx.x) * 2;
    const int j = blockIdx.y;
    const int b = blockIdx.z;
    const float2 td = *(const float2*)&time_decay[c0];
    const float2 tf = *(const float2*)&time_first[c0];
    const float d0 = 1.f / (1.f + expf(-td.x));
    const float d1 = 1.f / (1.f + expf(-td.y));
    const float f0 = expf(tf.x);
    const float f1 = expf(tf.y);

    float dL0 = d0, dL1 = d1;           // d^CHL, CHL=64 -> 6 squarings
    #pragma unroll
    for (int i = 0; i < 6; ++i) { dL0 *= dL0; dL1 *= dL1; }

    float s0 = 0.f, s1 = 0.f;
    for (int i = 0; i < j; ++i) {
        const float2 e = *(const float2*)&chend[((size_t)b * NCH + i) * C_ + c0];
        s0 = s0 * dL0 + e.x;
        s1 = s1 * dL1 + e.y;
    }

    size_t base = ((size_t)b * T_ + (size_t)j * CHL) * C_ + c0;
    #pragma unroll 4
    for (int t = 0; t < CHL; ++t) {
        const ushort2 kt = *(const ushort2*)&k[base];
        const ushort2 vt = *(const ushort2*)&v[base];
        const ushort2 rt = *(const ushort2*)&r[base];
        const float k0 = bf16_to_f32(kt.x), k1 = bf16_to_f32(kt.y);
        s0 = s0 * d0 + k0;
        s1 = s1 * d1 + k1;
        const float y0 = bf16_to_f32(rt.x) * ((s0 * f0 + k0) * bf16_to_f32(vt.x));
        const float y1 = bf16_to_f32(rt.y) * ((s1 * f1 + k1) * bf16_to_f32(vt.y));
        ushort2 ph; ph.x = rne_bf16(y0); ph.y = rne_bf16(y1);
        *(ushort2*)&yhi[base] = ph;
        base += C_;
    }
}

// ---------------- launch ----------------
extern "C" void kernel_launch(void* const* d_in, const int* in_sizes, int n_in,
                              void* d_out, int out_size, void* d_ws, size_t ws_size,
                              hipStream_t stream) {
    const float* x          = (const float*)d_in[0];
    const float* ln_w       = (const float*)d_in[1];
    const float* ln_b       = (const float*)d_in[2];
    const float* mix_k      = (const float*)d_in[3];
    const float* mix_v      = (const float*)d_in[4];
    const float* mix_r      = (const float*)d_in[5];
    const float* time_decay = (const float*)d_in[6];
    const float* time_first = (const float*)d_in[7];
    const float* Wk         = (const float*)d_in[8];
    const float* Wv         = (const float*)d_in[9];
    const float* Wr         = (const float*)d_in[10];
    const float* Wo         = (const float*)d_in[11];
    float* out = (float*)d_out;

    // ws (201.3 MB): ak | av | ar | kb | vb (bf16 planes, 33.5 MB each)
    //              | wr | wk | wv | wo (bf16 W planes, 8.4 MB each)
    // Post-proj reuse: yhi -> ak (dead), chend -> wr (dead); rb -> d_out bf16
    // (consumed by scan2 before gemm_out overwrites d_out with fp32).
    const size_t P = (size_t)M_ * C_;
    unsigned short* ak = (unsigned short*)d_ws;
    unsigned short* av = ak + P;
    unsigned short* ar = av + P;
    unsigned short* kb = ar + P;
    unsigned short* vb = kb + P;
    unsigned short* wr = vb + P;
    unsigned short* wk = wr + P / 4;
    unsigned short* wv = wk + P / 4;
    unsigned short* wo = wv + P / 4;

    unsigned short* rb = (unsigned short*)out;
    unsigned short* yhi = ak;
    float* chend = (float*)wr;

    const dim3 wkvGrid(C_ / 512, NCH, B_);

    // 1. fused prep: 4x W planes (16384 blocks) + LN/mix (8192 blocks)
    prep_kernel<<<16384 + M_, 256, 0, stream>>>(
        x, ln_w, ln_b, mix_k, mix_v, mix_r,
        Wr, Wk, Wv, Wo, wr, wk, wv, wo, ak, av, ar);

    // 2. merged r/k/v projection GEMM (768 blocks; r has sigmoid fused)
    gemm_proj3<<<768, 512, 0, stream>>>(ar, ak, av, wr, wk, wv, rb, kb, vb);

    // 3. WKV chunked scan -> y bf16 plane (yhi over ak; chend over wr)
    wkv_scan1<<<wkvGrid, 256, 0, stream>>>(kb, time_decay, chend);
    wkv_scan2<<<wkvGrid, 256, 0, stream>>>(kb, vb, rb, time_decay, time_first, chend,
                                           yhi);

    // 4. output projection -> fp32 d_out
    gemm_out<<<256, 512, 0, stream>>>(yhi, wo, out);
}